// Round 5
// baseline (1308.312 us; speedup 1.0000x reference)
//
#include <hip/hip_runtime.h>

#define NN 50000
#define NE 800000
#define H 256
#define NB (NE / 64)        // 12500 edge blocks
#define NBINS 50176         // NN padded

typedef __bf16 bf16x8 __attribute__((ext_vector_type(8)));
typedef __bf16 bf16x4 __attribute__((ext_vector_type(4)));
typedef float f32x4 __attribute__((ext_vector_type(4)));

static __device__ __forceinline__ f32x4 mfma16(bf16x8 a, bf16x8 b, f32x4 c) {
  return __builtin_amdgcn_mfma_f32_16x16x32_bf16(a, b, c, 0, 0, 0);
}
static __device__ __forceinline__ bf16x8 bzero8() {
  bf16x8 z;
#pragma unroll
  for (int j = 0; j < 8; ++j) z[j] = (__bf16)0.f;
  return z;
}
static __device__ __forceinline__ float silu_f(float v) {
  return v * __builtin_amdgcn_rcpf(1.f + __builtin_amdgcn_exp2f(v * -1.442695041f));
}
static __device__ __forceinline__ void add4(float4& a, const float4 b) {
  a.x += b.x; a.y += b.y; a.z += b.z; a.w += b.w;
}

// ---------------------------------------------------------------------------
// Merged prep: weight repack (fp32->bf16, [chunk][n][32k]) + cnt zero + tables.
// wsd: [3][8][512][32] (Ws|Wd of e1w rows 0..511), e2p/n2p: [3][8][256][32],
// n1p: [3][17][256][32] (K 528->544 pad), outp: [8][64][32].
// TR[l][8][256], TS/TD[l][24][256] (TD includes e1b).
// ---------------------------------------------------------------------------
__global__ void prep_kernel(
    const float* __restrict__ e1w, const float* __restrict__ e2w,
    const float* __restrict__ n1w, const float* __restrict__ n2w,
    const float* __restrict__ outw, const float* __restrict__ e1b,
    const float* __restrict__ rel_embs, const float* __restrict__ role_embs,
    const float* __restrict__ col_embs,
    __bf16* __restrict__ wsd, __bf16* __restrict__ e2p,
    __bf16* __restrict__ n1p, __bf16* __restrict__ n2p,
    __bf16* __restrict__ outp, int* __restrict__ cnt,
    float* __restrict__ TR, float* __restrict__ TS, float* __restrict__ TD)
{
  int i = blockIdx.x * 256 + threadIdx.x;
  if (i < 3 * 131072) {
    const int l = i / 131072, rem = i % 131072;
    const int c = rem >> 14, r2 = rem & 16383;
    const int n = r2 >> 5, k = c * 32 + (r2 & 31);
    wsd[i] = (n < 256) ? (__bf16)e1w[((size_t)l * 560 + k) * 256 + n]
                       : (__bf16)e1w[((size_t)l * 560 + 256 + k) * 256 + (n - 256)];
    return;
  }
  i -= 3 * 131072;
  if (i < 3 * 65536) {
    const int l = i / 65536, rem = i % 65536;
    const int c = rem >> 13, r2 = rem & 8191;
    const int n = r2 >> 5, k = c * 32 + (r2 & 31);
    e2p[i] = (__bf16)e2w[((size_t)l * 256 + k) * 256 + n];
    return;
  }
  i -= 3 * 65536;
  if (i < 3 * 139264) {
    const int l = i / 139264, rem = i % 139264;
    const int c = rem >> 13, r2 = rem & 8191;
    const int n = r2 >> 5, k = c * 32 + (r2 & 31);
    n1p[i] = (k < 528) ? (__bf16)n1w[((size_t)l * 528 + k) * 256 + n] : (__bf16)0.f;
    return;
  }
  i -= 3 * 139264;
  if (i < 3 * 65536) {
    const int l = i / 65536, rem = i % 65536;
    const int c = rem >> 13, r2 = rem & 8191;
    const int n = r2 >> 5, k = c * 32 + (r2 & 31);
    n2p[i] = (__bf16)n2w[((size_t)l * 256 + k) * 256 + n];
    return;
  }
  i -= 3 * 65536;
  if (i < 16384) {
    const int c = i >> 11, r2 = i & 2047;
    const int n = r2 >> 5, k = c * 32 + (r2 & 31);
    outp[i] = (__bf16)outw[(size_t)k * 64 + n];
    return;
  }
  i -= 16384;
  if (i < NBINS) { cnt[i] = 0; return; }
  i -= NBINS;
  if (i < 768) {
    const int l = i >> 8, c = i & 255;
    float w[48];
#pragma unroll
    for (int j = 0; j < 48; ++j) w[j] = e1w[((size_t)l * 560 + 512 + j) * 256 + c];
#pragma unroll
    for (int r = 0; r < 8; ++r) {
      float s = 0.f;
#pragma unroll
      for (int j = 0; j < 16; ++j) s += rel_embs[l * 128 + r * 16 + j] * w[j];
      TR[((size_t)l * 8 + r) * 256 + c] = s;
    }
    const float bias = e1b[l * 256 + c];
#pragma unroll
    for (int ro = 0; ro < 8; ++ro) {
      float ss = 0.f, sd = 0.f;
#pragma unroll
      for (int j = 0; j < 8; ++j) {
        ss += role_embs[l * 64 + ro * 8 + j] * w[16 + j];
        sd += role_embs[l * 64 + ro * 8 + j] * w[24 + j];
      }
#pragma unroll
      for (int co = 0; co < 3; ++co) {
        float cs = 0.f, cd = 0.f;
#pragma unroll
        for (int j = 0; j < 8; ++j) {
          cs += col_embs[l * 24 + co * 8 + j] * w[32 + j];
          cd += col_embs[l * 24 + co * 8 + j] * w[40 + j];
        }
        TS[((size_t)l * 24 + ro * 3 + co) * 256 + c] = ss + cs;
        TD[((size_t)l * 24 + ro * 3 + co) * 256 + c] = sd + cd + bias;
      }
    }
  }
}

// ---------------------------------------------------------------------------
// Counting sort by dst.
// ---------------------------------------------------------------------------
__global__ void hist_kernel(const int* __restrict__ dstI, int* __restrict__ cnt) {
  const int e = blockIdx.x * 256 + threadIdx.x;
  if (e < NE) atomicAdd(&cnt[dstI[e]], 1);
}

__global__ __launch_bounds__(1024) void scan_kernel(int* __restrict__ cnt) {
  __shared__ int wsum[16];
  __shared__ int carry;
  const int tid = threadIdx.x, lane = tid & 63, wid = tid >> 6;
  if (tid == 0) carry = 0;
  __syncthreads();
  for (int base = 0; base < NBINS; base += 4096) {
    const int idx = base + tid * 4;
    int4 v = make_int4(0, 0, 0, 0);
    if (idx < NBINS) v = *(const int4*)&cnt[idx];
    const int s1 = v.x + v.y, s2 = s1 + v.z, tot = s2 + v.w;
    int x = tot;
#pragma unroll
    for (int d = 1; d < 64; d <<= 1) {
      const int y = __shfl_up(x, d, 64);
      if (lane >= d) x += y;
    }
    if (lane == 63) wsum[wid] = x;
    __syncthreads();
    int wpref = 0;
#pragma unroll
    for (int w = 0; w < 16; ++w)
      if (w < wid) wpref += wsum[w];
    const int ex = carry + wpref + (x - tot);   // exclusive prefix of v.x
    if (idx < NBINS) {
      int4 o;
      o.x = ex; o.y = ex + v.x; o.z = ex + s1; o.w = ex + s2;
      *(int4*)&cnt[idx] = o;
    }
    __syncthreads();
    if (tid == 0) {
      int s = 0;
#pragma unroll
      for (int w = 0; w < 16; ++w) s += wsum[w];
      carry += s;
    }
    __syncthreads();
  }
}

// After scatter, cnt[d] = end offset of d's run (start = cnt[d-1]).
__global__ void scatter_kernel(const int* __restrict__ srcI, const int* __restrict__ dstI,
                               const int* __restrict__ erel, int* __restrict__ cnt,
                               int* __restrict__ esr, int* __restrict__ dstS) {
  const int e = blockIdx.x * 256 + threadIdx.x;
  if (e < NE) {
    const int d = dstI[e];
    const int pos = atomicAdd(&cnt[d], 1);
    esr[pos] = srcI[e] | (erel[e] << 16);   // src < 65536, rel < 8
    dstS[pos] = d;
  }
}

// ---------------------------------------------------------------------------
// Input embedding.
// ---------------------------------------------------------------------------
__global__ __launch_bounds__(256) void embed_kernel(
    const float* __restrict__ scalars, const int* __restrict__ ncol,
    const int* __restrict__ nrole,
    const float* __restrict__ colEmb, const float* __restrict__ roleEmb,
    const float* __restrict__ inw, const float* __restrict__ inb,
    __bf16* __restrict__ h)
{
  __shared__ float sW[32][256];
  __shared__ float sIn[16][32];
  const int tid = threadIdx.x;
  const int n0 = blockIdx.x * 16;
#pragma unroll
  for (int j = 0; j < 32; ++j) sW[j][tid] = inw[j * 256 + tid];
  {
    const int node = tid >> 4, k = tid & 15;
    const int n = n0 + node;
    sIn[node][k] = (n < NN) ? scalars[(size_t)n * 16 + k] : 0.f;
  }
  if (tid < 16) {
    const int n = n0 + tid;
    if (n < NN) {
      const int c = ncol[n], r = nrole[n];
#pragma unroll
      for (int j = 0; j < 8; ++j) {
        sIn[tid][16 + j] = colEmb[c * 8 + j];
        sIn[tid][24 + j] = roleEmb[r * 8 + j];
      }
    } else {
#pragma unroll
      for (int j = 0; j < 16; ++j) sIn[tid][16 + j] = 0.f;
    }
  }
  __syncthreads();
  const float bias = inb[tid];
  for (int nn = 0; nn < 16; ++nn) {
    const int n = n0 + nn;
    if (n >= NN) break;
    float acc = bias;
#pragma unroll
    for (int k = 0; k < 32; ++k) acc += sIn[nn][k] * sW[k][tid];
    h[(size_t)n * H + tid] = (__bf16)acc;
  }
}

// ---------------------------------------------------------------------------
// Layer-0 node projections: PS = h@Ws + TS[role,col]; PD = h@Wd + TD (b1 in TD).
// ---------------------------------------------------------------------------
__global__ __launch_bounds__(256, 4) void pre_kernel(
    const __bf16* __restrict__ h, const int* __restrict__ nrole,
    const int* __restrict__ ncol, const __bf16* __restrict__ wsd,
    const float* __restrict__ TS, const float* __restrict__ TD,
    __bf16* __restrict__ PS, __bf16* __restrict__ PD)
{
  __shared__ __align__(16) __bf16 Ah[64][72];
  const int tid  = threadIdx.x;
  const int lane = tid & 63;
  const int wave = tid >> 6;
  const int l15  = lane & 15;
  const int quad = lane >> 4;
  const int n0   = (blockIdx.x >> 1) * 64;
  const int half = blockIdx.x & 1;
  const int colW = wave * 64;

  f32x4 acc[4][4] = {};
  for (int s = 0; s < 4; ++s) {
    if (s) __syncthreads();
#pragma unroll
    for (int it = 0; it < 2; ++it) {
      const int t = tid + it * 256;
      const int row = t >> 3, seg = t & 7;
      const int n = n0 + row;
      bf16x8 v = bzero8();
      if (n < NN) v = *(const bf16x8*)(h + (size_t)n * H + s * 64 + seg * 8);
      *(bf16x8*)&Ah[row][seg * 8] = v;
    }
    __syncthreads();
#pragma unroll
    for (int cc = 0; cc < 2; ++cc) {
      const int c = 2 * s + cc;
      bf16x8 bfr[4], afr[4];
#pragma unroll
      for (int nj = 0; nj < 4; ++nj)
        bfr[nj] = *(const bf16x8*)(wsd + ((size_t)c * 512 + half * 256 + colW + nj * 16 + l15) * 32 + quad * 8);
#pragma unroll
      for (int mi = 0; mi < 4; ++mi)
        afr[mi] = *(const bf16x8*)&Ah[mi * 16 + l15][cc * 32 + quad * 8];
#pragma unroll
      for (int mi = 0; mi < 4; ++mi)
#pragma unroll
        for (int nj = 0; nj < 4; ++nj)
          acc[mi][nj] = mfma16(afr[mi], bfr[nj], acc[mi][nj]);
    }
  }

  const float* T = half ? TD : TS;
  __bf16* P = half ? PD : PS;
#pragma unroll
  for (int mi = 0; mi < 4; ++mi)
#pragma unroll
    for (int r = 0; r < 4; ++r) {
      const int n = n0 + mi * 16 + quad * 4 + r;
      if (n < NN) {
        const int ti = (nrole[n] * 3 + ncol[n]) * 256;
#pragma unroll
        for (int nj = 0; nj < 4; ++nj) {
          const int col = colW + nj * 16 + l15;
          P[(size_t)n * H + col] = (__bf16)(acc[mi][nj][r] + T[ti + col]);
        }
      }
    }
}

// ---------------------------------------------------------------------------
// Fused edge MLP + segmented scatter (edges sorted by dst, no atomics):
//   m1 = silu(PS[src] + PD[dst] + TR[rel]); m2 = silu(m1 @ e2w + e2b)
//   interior segments -> plain store to agg; block's first/last segment
//   partials -> bnd[2b]/bnd[2b+1] (always both written; single-seg -> 2b+1).
// ---------------------------------------------------------------------------
__global__ __launch_bounds__(256, 4) void edge_kernel(
    const __bf16* __restrict__ PS, const __bf16* __restrict__ PD,
    float* __restrict__ agg, float* __restrict__ bnd,
    const int* __restrict__ esr, const int* __restrict__ dstS,
    const float* __restrict__ TR,
    const __bf16* __restrict__ e2p, const float* __restrict__ e2b)
{
  __shared__ __align__(16) char uni[34816];
  __shared__ __bf16 sTrel[8][256];
  __shared__ int sSrc[64], sDst[64], sRel[64];

  auto A2  = (__bf16 (*)[264])uni;      // [64][264]  m1 row-major
  auto A2t = (__bf16 (*)[68])uni;       // [256][68]  m2 col-major (aliased)

  const int tid  = threadIdx.x;
  const int lane = tid & 63;
  const int wave = tid >> 6;
  const int l15  = lane & 15;
  const int quad = lane >> 4;
  const int e0   = blockIdx.x * 64;
  const int colW = wave * 64;

  if (tid < 64) {
    const int u = esr[e0 + tid];
    sSrc[tid] = u & 0xffff;
    sRel[tid] = u >> 16;
    sDst[tid] = dstS[e0 + tid];
  }
  {
    const int r = tid >> 5, cs = (tid & 31) * 8;
    const float* p = TR + r * 256 + cs;
    bf16x8 v;
#pragma unroll
    for (int j = 0; j < 8; ++j) v[j] = (__bf16)p[j];
    *(bf16x8*)&sTrel[r][cs] = v;
  }
  __syncthreads();

  // ---- m1 ----
  {
    const int brow = tid >> 5;
    const int cs = (tid & 31) * 8;
#pragma unroll
    for (int it = 0; it < 8; ++it) {
      const int row = it * 8 + brow;
      const bf16x8 a = *(const bf16x8*)(PS + (size_t)sSrc[row] * H + cs);
      const bf16x8 b = *(const bf16x8*)(PD + (size_t)sDst[row] * H + cs);
      const bf16x8 t = *(const bf16x8*)&sTrel[sRel[row]][cs];
      bf16x8 o;
#pragma unroll
      for (int j = 0; j < 8; ++j)
        o[j] = (__bf16)silu_f((float)a[j] + (float)b[j] + (float)t[j]);
      *(bf16x8*)&A2[row][cs] = o;
    }
  }
  __syncthreads();

  // ---- GEMM2 ----
  f32x4 acc2[4][4] = {};
#pragma unroll
  for (int c = 0; c < 8; ++c) {
    bf16x8 bfr[4], afr[4];
#pragma unroll
    for (int nj = 0; nj < 4; ++nj)
      bfr[nj] = *(const bf16x8*)(e2p + ((size_t)c * 256 + colW + nj * 16 + l15) * 32 + quad * 8);
#pragma unroll
    for (int mi = 0; mi < 4; ++mi)
      afr[mi] = *(const bf16x8*)&A2[mi * 16 + l15][c * 32 + quad * 8];
#pragma unroll
    for (int mi = 0; mi < 4; ++mi)
#pragma unroll
      for (int nj = 0; nj < 4; ++nj)
        acc2[mi][nj] = mfma16(afr[mi], bfr[nj], acc2[mi][nj]);
  }

  float b2[4];
#pragma unroll
  for (int nj = 0; nj < 4; ++nj) b2[nj] = e2b[colW + nj * 16 + l15];
  __syncthreads();   // A2 reads done before A2t (aliased) write

  // ---- m2 transposed into A2t[col][row] ----
#pragma unroll
  for (int mi = 0; mi < 4; ++mi)
#pragma unroll
    for (int nj = 0; nj < 4; ++nj) {
      const int col = colW + nj * 16 + l15;
      bf16x4 pv;
#pragma unroll
      for (int r = 0; r < 4; ++r)
        pv[r] = (__bf16)silu_f(acc2[mi][nj][r] + b2[nj]);
      *(bf16x4*)&A2t[col][mi * 16 + quad * 4] = pv;
    }
  __syncthreads();

  // ---- segmented reduce: thread = column; all plain stores ----
  {
    const int col = tid;
    const bool f = (lane > 0) && (sDst[lane] != sDst[lane - 1]);
    const unsigned long long mask = __ballot(f);
    bf16x4 v[16];
#pragma unroll
    for (int j = 0; j < 16; ++j) v[j] = *(const bf16x4*)&A2t[col][j * 4];
    float* bnd0 = bnd + ((size_t)2 * blockIdx.x) * 256 + col;
    float sum = 0.f;
    int s0 = 0;
#pragma unroll
    for (int r = 0; r < 64; ++r) {
      sum += (float)v[r >> 2][r & 3];
      if (r == 63 || ((mask >> (r + 1)) & 1ull)) {
        const bool isFirst = (s0 == 0), isLast = (r == 63);
        if (isFirst) {
          bnd0[0] = isLast ? 0.f : sum;        // single-seg convention: 2b=0
          if (isLast) bnd0[256] = sum;         //                        2b+1=sum
        } else if (isLast) {
          bnd0[256] = sum;
        } else {
          agg[(size_t)sDst[r] * H + col] = sum;
        }
        sum = 0.f;
        s0 = r + 1;
      }
    }
  }
}

// ---------------------------------------------------------------------------
// Fused node update + (mode 0) next-layer PS/PD or (mode 1) output projection.
// agg reconstruction: interior -> agg row; spanning -> sum of bnd pieces.
// ---------------------------------------------------------------------------
__global__ __launch_bounds__(256, 4) void node_kernel(
    __bf16* __restrict__ h, const float* __restrict__ agg,
    const float* __restrict__ bnd, const int* __restrict__ cnt,
    const int* __restrict__ nrole, const int* __restrict__ ncol,
    const float* __restrict__ roleE, const float* __restrict__ colE,
    const __bf16* __restrict__ n1p, const float* __restrict__ n1b,
    const __bf16* __restrict__ n2p, const float* __restrict__ n2b,
    const float* __restrict__ lng, const float* __restrict__ lnb,
    const int mode,
    const __bf16* __restrict__ wsdN, const float* __restrict__ TSn,
    const float* __restrict__ TDn, __bf16* __restrict__ PS, __bf16* __restrict__ PD,
    const __bf16* __restrict__ outp, const float* __restrict__ outb,
    float* __restrict__ out)
{
  __shared__ __align__(16) char uni[33792];
  __shared__ __bf16 sRole[8][8], sCol[3][8];
  __shared__ float sSum[64][4], sSsq[64][4];
  __shared__ int sStart[64], sEnd[64], sTi[64];

  auto Abuf = (__bf16 (*)[72])uni;   // [64][72]   GEMM1 staging
  auto A2   = (__bf16 (*)[264])uni;  // [64][264]  GEMM1 out / h_new for P-GEMM

  const int tid  = threadIdx.x;
  const int lane = tid & 63;
  const int wave = tid >> 6;
  const int l15  = lane & 15;
  const int quad = lane >> 4;
  const int n0   = blockIdx.x * 64;
  const int colW = wave * 64;

  if (tid < 64) {
    const int n = n0 + tid;
    int st = 0, en = 0, ti = 0;
    if (n < NN) {
      st = (n > 0) ? cnt[n - 1] : 0;
      en = cnt[n];
      ti = (nrole[n] * 3 + ncol[n]) * 256;
    }
    sStart[tid] = st; sEnd[tid] = en; sTi[tid] = ti;
    ((__bf16*)sRole)[tid] = (__bf16)roleE[tid];
  } else if (tid < 88) {
    ((__bf16*)sCol)[tid - 64] = (__bf16)colE[tid - 64];
  }
  __syncthreads();

  f32x4 acc[4][4] = {};
  for (int s = 0; s < 9; ++s) {
    if (s) __syncthreads();
    if (s < 4) {
#pragma unroll
      for (int it = 0; it < 2; ++it) {
        const int t = tid + it * 256;
        const int row = t >> 3, seg = t & 7;
        const int n = n0 + row;
        bf16x8 v = bzero8();
        if (n < NN) v = *(const bf16x8*)(h + (size_t)n * H + s * 64 + seg * 8);
        *(bf16x8*)&Abuf[row][seg * 8] = v;
      }
    } else if (s < 8) {
#pragma unroll
      for (int it = 0; it < 2; ++it) {
        const int t = tid + it * 256;
        const int row = t >> 3, seg = t & 7;
        const int off = (s - 4) * 64 + seg * 8;
        const int st = sStart[row], en = sEnd[row];
        float4 u0 = make_float4(0.f, 0.f, 0.f, 0.f);
        float4 u1 = make_float4(0.f, 0.f, 0.f, 0.f);
        if (en > st) {
          const int bs = st >> 6, be = (en - 1) >> 6;
          const bool interior = (bs == be) && (st & 63) != 0 && (en & 63) != 0;
          if (interior) {
            const float* p = agg + (size_t)(n0 + row) * H + off;
            u0 = *(const float4*)p;
            u1 = *(const float4*)(p + 4);
          } else {
            for (int b = bs; b <= be; ++b) {
              if (b > bs || (st & 63) == 0) {
                const float* p = bnd + ((size_t)2 * b) * 256 + off;
                add4(u0, *(const float4*)p);
                add4(u1, *(const float4*)(p + 4));
              }
              if (b < be || (en & 63) == 0) {
                const float* p = bnd + ((size_t)2 * b + 1) * 256 + off;
                add4(u0, *(const float4*)p);
                add4(u1, *(const float4*)(p + 4));
              }
            }
          }
        }
        bf16x8 v;
        v[0] = (__bf16)u0.x; v[1] = (__bf16)u0.y; v[2] = (__bf16)u0.z; v[3] = (__bf16)u0.w;
        v[4] = (__bf16)u1.x; v[5] = (__bf16)u1.y; v[6] = (__bf16)u1.z; v[7] = (__bf16)u1.w;
        *(bf16x8*)&Abuf[row][seg * 8] = v;
      }
    } else {
      const int row = tid >> 2, q = tid & 3;
      const int n = n0 + row;
      __bf16* dp = &Abuf[row][q * 16];
      if (q == 0 && n < NN) {
        const int r = nrole[n], c = ncol[n];
#pragma unroll
        for (int j = 0; j < 8; ++j) { dp[j] = sRole[r][j]; dp[8 + j] = sCol[c][j]; }
      } else {
#pragma unroll
        for (int j = 0; j < 16; ++j) dp[j] = (__bf16)0.f;
      }
    }
    __syncthreads();
#pragma unroll
    for (int cc = 0; cc < 2; ++cc) {
      const int c = 2 * s + cc;
      if (c >= 17) break;
      bf16x8 bfr[4], afr[4];
#pragma unroll
      for (int nj = 0; nj < 4; ++nj)
        bfr[nj] = *(const bf16x8*)(n1p + ((size_t)c * 256 + colW + nj * 16 + l15) * 32 + quad * 8);
#pragma unroll
      for (int mi = 0; mi < 4; ++mi)
        afr[mi] = *(const bf16x8*)&Abuf[mi * 16 + l15][cc * 32 + quad * 8];
#pragma unroll
      for (int mi = 0; mi < 4; ++mi)
#pragma unroll
        for (int nj = 0; nj < 4; ++nj)
          acc[mi][nj] = mfma16(afr[mi], bfr[nj], acc[mi][nj]);
    }
  }
  __syncthreads();   // Abuf reads done before A2 (aliased) write

  float b1[4];
#pragma unroll
  for (int nj = 0; nj < 4; ++nj) b1[nj] = n1b[colW + nj * 16 + l15];
#pragma unroll
  for (int mi = 0; mi < 4; ++mi)
#pragma unroll
    for (int nj = 0; nj < 4; ++nj)
#pragma unroll
      for (int r = 0; r < 4; ++r)
        A2[mi * 16 + quad * 4 + r][colW + nj * 16 + l15] =
            (__bf16)silu_f(acc[mi][nj][r] + b1[nj]);
  __syncthreads();

  f32x4 acc2[4][4] = {};
#pragma unroll
  for (int c = 0; c < 8; ++c) {
    bf16x8 bfr[4], afr[4];
#pragma unroll
    for (int nj = 0; nj < 4; ++nj)
      bfr[nj] = *(const bf16x8*)(n2p + ((size_t)c * 256 + colW + nj * 16 + l15) * 32 + quad * 8);
#pragma unroll
    for (int mi = 0; mi < 4; ++mi)
      afr[mi] = *(const bf16x8*)&A2[mi * 16 + l15][c * 32 + quad * 8];
#pragma unroll
    for (int mi = 0; mi < 4; ++mi)
#pragma unroll
      for (int nj = 0; nj < 4; ++nj)
        acc2[mi][nj] = mfma16(afr[mi], bfr[nj], acc2[mi][nj]);
  }

  float b2[4], g4[4], bb4[4];
#pragma unroll
  for (int nj = 0; nj < 4; ++nj) {
    const int col = colW + nj * 16 + l15;
    b2[nj] = n2b[col]; g4[nj] = lng[col]; bb4[nj] = lnb[col];
  }
#pragma unroll
  for (int mi = 0; mi < 4; ++mi)
#pragma unroll
    for (int r = 0; r < 4; ++r) {
      const int n = n0 + mi * 16 + quad * 4 + r;
#pragma unroll
      for (int nj = 0; nj < 4; ++nj) {
        const float hv = (n < NN) ? (float)h[(size_t)n * H + colW + nj * 16 + l15] : 0.f;
        acc2[mi][nj][r] += b2[nj] + hv;
      }
    }
#pragma unroll
  for (int mi = 0; mi < 4; ++mi)
#pragma unroll
    for (int r = 0; r < 4; ++r) {
      float s1 = 0.f, s2 = 0.f;
#pragma unroll
      for (int nj = 0; nj < 4; ++nj) {
        const float v = acc2[mi][nj][r];
        s1 += v; s2 += v * v;
      }
#pragma unroll
      for (int d = 1; d < 16; d <<= 1) {
        s1 += __shfl_xor(s1, d, 16);
        s2 += __shfl_xor(s2, d, 16);
      }
      if (l15 == 0) {
        const int row = mi * 16 + quad * 4 + r;
        sSum[row][wave] = s1; sSsq[row][wave] = s2;
      }
    }
  __syncthreads();   // also: all GEMM2 A2 reads complete -> A2 reusable as h_new

#pragma unroll
  for (int mi = 0; mi < 4; ++mi)
#pragma unroll
    for (int r = 0; r < 4; ++r) {
      const int row = mi * 16 + quad * 4 + r;
      const int n = n0 + row;
      const float t1 = sSum[row][0] + sSum[row][1] + sSum[row][2] + sSum[row][3];
      const float t2 = sSsq[row][0] + sSsq[row][1] + sSsq[row][2] + sSsq[row][3];
      const float mu = t1 * (1.f / 256.f);
      float var = t2 * (1.f / 256.f) - mu * mu;
      var = var < 0.f ? 0.f : var;
      const float rstd = rsqrtf(var + 1e-5f);
#pragma unroll
      for (int nj = 0; nj < 4; ++nj) {
        const int col = colW + nj * 16 + l15;
        const float o = g4[nj] * (acc2[mi][nj][r] - mu) * rstd + bb4[nj];
        const __bf16 ob = (__bf16)o;
        A2[row][col] = ob;                                   // h_new for P/out GEMM
        if (mode == 0 && n < NN) h[(size_t)n * H + col] = ob;
      }
    }
  __syncthreads();   // h_new staged in A2

  if (mode == 0) {
    // ---- next-layer PS/PD: P = h_new @ (Ws|Wd) + tables ----
    for (int hf = 0; hf < 2; ++hf) {
      f32x4 ap[4][4] = {};
#pragma unroll
      for (int c = 0; c < 8; ++c) {
        bf16x8 bfr[4], afr[4];
#pragma unroll
        for (int nj = 0; nj < 4; ++nj)
          bfr[nj] = *(const bf16x8*)(wsdN + ((size_t)c * 512 + hf * 256 + colW + nj * 16 + l15) * 32 + quad * 8);
#pragma unroll
        for (int mi = 0; mi < 4; ++mi)
          afr[mi] = *(const bf16x8*)&A2[mi * 16 + l15][c * 32 + quad * 8];
#pragma unroll
        for (int mi = 0; mi < 4; ++mi)
#pragma unroll
          for (int nj = 0; nj < 4; ++nj)
            ap[mi][nj] = mfma16(afr[mi], bfr[nj], ap[mi][nj]);
      }
      const float* T = hf ? TDn : TSn;
      __bf16* P = hf ? PD : PS;
#pragma unroll
      for (int mi = 0; mi < 4; ++mi)
#pragma unroll
        for (int r = 0; r < 4; ++r) {
          const int row = mi * 16 + quad * 4 + r;
          const int n = n0 + row;
          if (n < NN) {
            const int ti = sTi[row];
#pragma unroll
            for (int nj = 0; nj < 4; ++nj) {
              const int col = colW + nj * 16 + l15;
              P[(size_t)n * H + col] = (__bf16)(ap[mi][nj][r] + T[ti + col]);
            }
          }
        }
    }
  } else {
    // ---- output projection: out = h_new @ out_w + out_b (wave w: cols 16w..) ----
    f32x4 ao[4] = {};
#pragma unroll
    for (int c = 0; c < 8; ++c) {
      const bf16x8 bfr = *(const bf16x8*)(outp + ((size_t)c * 64 + wave * 16 + l15) * 32 + quad * 8);
#pragma unroll
      for (int mi = 0; mi < 4; ++mi) {
        const bf16x8 afr = *(const bf16x8*)&A2[mi * 16 + l15][c * 32 + quad * 8];
        ao[mi] = mfma16(afr, bfr, ao[mi]);
      }
    }
    const float ob = outb[wave * 16 + l15];
#pragma unroll
    for (int mi = 0; mi < 4; ++mi)
#pragma unroll
      for (int r = 0; r < 4; ++r) {
        const int n = n0 + mi * 16 + quad * 4 + r;
        if (n < NN) out[(size_t)n * 64 + wave * 16 + l15] = ao[mi][r] + ob;
      }
  }
}

// ---------------------------------------------------------------------------
extern "C" void kernel_launch(void* const* d_in, const int* in_sizes, int n_in,
                              void* d_out, int out_size, void* d_ws, size_t ws_size,
                              hipStream_t stream) {
  const float* scalars   = (const float*)d_in[0];
  const int*   ei        = (const int*)d_in[1];
  const int*   erel      = (const int*)d_in[2];
  const int*   ncol      = (const int*)d_in[3];
  const int*   nrole     = (const int*)d_in[4];
  const float* blk_role  = (const float*)d_in[5];
  const float* blk_col   = (const float*)d_in[6];
  const float* inw       = (const float*)d_in[7];
  const float* inb       = (const float*)d_in[8];
  const float* rel_embs  = (const float*)d_in[9];
  const float* role_embs = (const float*)d_in[10];
  const float* col_embs  = (const float*)d_in[11];
  const float* e1w       = (const float*)d_in[12];
  const float* e1b       = (const float*)d_in[13];
  const float* e2w       = (const float*)d_in[14];
  const float* e2b       = (const float*)d_in[15];
  const float* n1w       = (const float*)d_in[16];
  const float* n1b       = (const float*)d_in[17];
  const float* n2w       = (const float*)d_in[18];
  const float* n2b       = (const float*)d_in[19];
  const float* lng       = (const float*)d_in[20];
  const float* lnb       = (const float*)d_in[21];
  const float* outw      = (const float*)d_in[22];
  const float* outb      = (const float*)d_in[23];

  const int* srcI = ei;
  const int* dstI = ei + NE;

  char* ws = (char*)d_ws;
  size_t off = 0;
  auto take = [&](size_t bytes) -> char* {
    off = (off + 255) & ~(size_t)255;
    char* p = ws + off;
    off += bytes;
    return p;
  };
  __bf16* h    = (__bf16*)take((size_t)NN * H * 2);
  float*  agg  = (float*)take((size_t)NN * H * 4);
  float*  bnd  = (float*)take((size_t)2 * NB * 256 * 4);
  __bf16* PS   = (__bf16*)take((size_t)NN * H * 2);
  __bf16* PD   = (__bf16*)take((size_t)NN * H * 2);
  __bf16* wsd  = (__bf16*)take((size_t)3 * 131072 * 2);
  __bf16* e2p  = (__bf16*)take((size_t)3 * 65536 * 2);
  __bf16* n1p  = (__bf16*)take((size_t)3 * 139264 * 2);
  __bf16* n2p  = (__bf16*)take((size_t)3 * 65536 * 2);
  __bf16* outp = (__bf16*)take((size_t)16384 * 2);
  float*  TR   = (float*)take((size_t)3 * 8 * 256 * 4);
  float*  TS   = (float*)take((size_t)3 * 24 * 256 * 4);
  float*  TD   = (float*)take((size_t)3 * 24 * 256 * 4);
  int*    cnt  = (int*)take((size_t)NBINS * 4);
  int*    esr  = (int*)take((size_t)NE * 4);
  int*    dstS = (int*)take((size_t)NE * 4);

  prep_kernel<<<4967, 256, 0, stream>>>(e1w, e2w, n1w, n2w, outw, e1b,
                                        rel_embs, role_embs, col_embs,
                                        wsd, e2p, n1p, n2p, outp, cnt, TR, TS, TD);
  hist_kernel<<<(NE + 255) / 256, 256, 0, stream>>>(dstI, cnt);
  scan_kernel<<<1, 1024, 0, stream>>>(cnt);
  scatter_kernel<<<(NE + 255) / 256, 256, 0, stream>>>(srcI, dstI, erel, cnt,
                                                       esr, dstS);
  embed_kernel<<<(NN + 15) / 16, 256, 0, stream>>>(scalars, ncol, nrole,
                                                   blk_col, blk_role, inw, inb, h);
  pre_kernel<<<2 * ((NN + 63) / 64), 256, 0, stream>>>(
      h, nrole, ncol, wsd, TS, TD, PS, PD);

  for (int l = 0; l < 3; ++l) {
    edge_kernel<<<NB, 256, 0, stream>>>(
        PS, PD, agg, bnd, esr, dstS, TR + (size_t)l * 2048,
        e2p + (size_t)l * 65536, e2b + (size_t)l * 256);
    const int mode = (l < 2) ? 0 : 1;
    node_kernel<<<(NN + 63) / 64, 256, 0, stream>>>(
        h, agg, bnd, cnt, nrole, ncol,
        role_embs + (size_t)l * 64, col_embs + (size_t)l * 24,
        n1p + (size_t)l * 139264, n1b + (size_t)l * 256,
        n2p + (size_t)l * 65536,  n2b + (size_t)l * 256,
        lng + (size_t)l * 256, lnb + (size_t)l * 256,
        mode,
        wsd + (size_t)(l + 1 < 3 ? l + 1 : 0) * 131072,
        TS + (size_t)(l + 1 < 3 ? l + 1 : 0) * 6144,
        TD + (size_t)(l + 1 < 3 ? l + 1 : 0) * 6144,
        PS, PD, outp, outb, (float*)d_out);
  }
}